// Round 10
// baseline (501.861 us; speedup 1.0000x reference)
//
#include <hip/hip_runtime.h>
#include <math.h>

#define NN 100000
#define NE 3200000
#define OUTD 112
#define BROWS 512                 // rows per bucket (9-bit local row)
#define NBUCK 196                 // ceil(NN / BROWS)
#define FILL_CH 8192              // edges per block in hist/fill
#define FILL_B ((NE + FILL_CH - 1) / FILL_CH)   // 391
#define BLD1_T 1024               // threads for prep/bucket_fill (16 waves)
#define SORT_T 1024               // threads for csr_sort scatter
#define FUSE_B ((NN * 16 + BLD1_T - 1) / BLD1_T)   // 1563 fuse blocks (4 feat/thr)

// round-to-nearest-even fp32 -> bf16 (as raw 16 bits)
__device__ inline unsigned short f32_to_bf16(float f) {
    unsigned u = __float_as_uint(f);
    u += 0x7FFFu + ((u >> 16) & 1u);
    return (unsigned short)(u >> 16);
}
__device__ inline float bf16_bits_to_f32(unsigned b) {
    return __uint_as_float(b << 16);
}

// ---------------------------------------------------------------------------
// MERGED prep kernel: blocks [0, FILL_B) do the bucket histogram (persisting
// per-block counts to bhistT); blocks [FILL_B, FILL_B+FUSE_B) do the
// holographic fusion, VECTORIZED: 4 features per thread (3x float4 W loads,
// float4 entity/out, ushort4 ego0h).
// ---------------------------------------------------------------------------
__global__ __launch_bounds__(BLD1_T) void prep_kernel(
    const int* __restrict__ rows,
    int* __restrict__ gcount,
    int* __restrict__ bhistT,
    const float* __restrict__ aux_info,
    const float* __restrict__ entity,
    const float* __restrict__ aux_W,
    const float* __restrict__ aux_b,
    unsigned short* __restrict__ ego0h,
    float* __restrict__ out)
{
    __shared__ int h[NBUCK];
    if (blockIdx.x < FILL_B) {
        // ---- bhist part ----
        for (int i = threadIdx.x; i < NBUCK; i += BLD1_T) h[i] = 0;
        __syncthreads();
        int base = blockIdx.x * FILL_CH;
        int nE = NE - base; if (nE > FILL_CH) nE = FILL_CH;
        for (int i = threadIdx.x; i < nE; i += BLD1_T)
            atomicAdd(&h[rows[base + i] >> 9], 1);
        __syncthreads();
        for (int i = threadIdx.x; i < NBUCK; i += BLD1_T) {
            int c = h[i];
            bhistT[i * FILL_B + blockIdx.x] = c;
            if (c) atomicAdd(&gcount[i], c);
        }
    } else {
        // ---- fuse_ego part: thread = (node n, feature quad j0=4q) ----
        int idx = (blockIdx.x - FILL_B) * BLD1_T + threadIdx.x;
        if (idx >= NN * 16) return;
        int n  = idx >> 4;
        int j0 = (idx & 15) * 4;
        float a0 = aux_info[n * 3 + 0];
        float a1 = aux_info[n * 3 + 1];
        float a2 = aux_info[n * 3 + 2];
        float4 w0 = *(const float4*)&aux_W[j0 * 3 + 0];   // 12 floats = rows j0..j0+3
        float4 w1 = *(const float4*)&aux_W[j0 * 3 + 4];
        float4 w2 = *(const float4*)&aux_W[j0 * 3 + 8];
        float4 bq = *(const float4*)&aux_b[j0];
        float4 ev = *(const float4*)&entity[(size_t)n * 64 + j0];
        float4 r;
        r.x = ev.x * (1.0f + tanhf(fmaf(a0, w0.x, fmaf(a1, w0.y, fmaf(a2, w0.z, bq.x)))));
        r.y = ev.y * (1.0f + tanhf(fmaf(a0, w0.w, fmaf(a1, w1.x, fmaf(a2, w1.y, bq.y)))));
        r.z = ev.z * (1.0f + tanhf(fmaf(a0, w1.z, fmaf(a1, w1.w, fmaf(a2, w2.x, bq.z)))));
        r.w = ev.w * (1.0f + tanhf(fmaf(a0, w2.y, fmaf(a1, w2.z, fmaf(a2, w2.w, bq.w)))));
        ushort4 hq;
        hq.x = f32_to_bf16(r.x);
        hq.y = f32_to_bf16(r.y);
        hq.z = f32_to_bf16(r.z);
        hq.w = f32_to_bf16(r.w);
        *(ushort4*)&ego0h[(size_t)n * 64 + j0] = hq;
        *(float4*)&out[(size_t)n * OUTD + j0] = r;
    }
}

// ---------------------------------------------------------------------------
// CSR build, stage 1b: per-bucket exclusive scan over block counts, with the
// bucket-level scan folded in.
// ---------------------------------------------------------------------------
__global__ void cursor_scan_kernel(const int* __restrict__ bhistT,
                                   const int* __restrict__ gcount,
                                   int* __restrict__ bucket_base,
                                   int* __restrict__ cursor) {
    static_assert(FILL_B <= 512, "scan width");
    __shared__ int sh[512];
    __shared__ int bb[256];
    int b = blockIdx.x;            // bucket
    int t = threadIdx.x;           // chunk-block index
    int gv = (t < NBUCK) ? gcount[t] : 0;
    if (t < 256) bb[t] = gv;
    __syncthreads();
    for (int off = 1; off < 256; off <<= 1) {
        int u = (t >= off && t < 256) ? bb[t - off] : 0;
        __syncthreads();
        if (t < 256) bb[t] += u;
        __syncthreads();
    }
    int base_b = (b > 0) ? bb[b - 1] : 0;     // exclusive prefix for bucket b
    if (t == 0) bucket_base[b] = base_b;
    if (b == 0 && t == 0) bucket_base[NBUCK] = bb[NBUCK - 1];
    int v = (t < FILL_B) ? bhistT[b * FILL_B + t] : 0;
    sh[t] = v;
    __syncthreads();
    for (int off = 1; off < 512; off <<= 1) {
        int u = (t >= off) ? sh[t - off] : 0;
        __syncthreads();
        sh[t] += u;
        __syncthreads();
    }
    if (t < FILL_B) cursor[b * FILL_B + t] = base_b + sh[t] - v;
}

// ---------------------------------------------------------------------------
// CSR build, stage 1c: single-pass scatter to SoA bucket order. ALSO counts
// per-row edges via fire-and-forget global atomics (rcount, 100k addresses,
// low contention) — this kills csr_sort's count pass + 512-wide scan.
// cols/vals are pure streams -> nontemporal loads (don't pollute L2).
// ---------------------------------------------------------------------------
__global__ void bucket_fill_kernel(const int* __restrict__ rows,
                                   const int* __restrict__ cols,
                                   const float* __restrict__ vals,
                                   const int* __restrict__ cursor,
                                   int* __restrict__ rcount,
                                   unsigned int* __restrict__ bkeys,
                                   float* __restrict__ bvals) {
    __shared__ int curs[NBUCK];
    int base = blockIdx.x * FILL_CH;
    int nE = NE - base; if (nE > FILL_CH) nE = FILL_CH;
    for (int i = threadIdx.x; i < NBUCK; i += BLD1_T)
        curs[i] = cursor[i * FILL_B + blockIdx.x];
    __syncthreads();
    for (int i = threadIdx.x; i < nE; i += BLD1_T) {
        int r = rows[base + i];
        int c = __builtin_nontemporal_load(&cols[base + i]);
        float v = __builtin_nontemporal_load(&vals[base + i]);
        int p = atomicAdd(&curs[r >> 9], 1);
        bkeys[p] = (unsigned int)c | ((r & (BROWS - 1)) << 17);
        bvals[p] = v;
        atomicAdd(&rcount[r], 1);   // no return value -> fire-and-forget
    }
}

// ---------------------------------------------------------------------------
// NEW: row_scan — per-bucket scan of rcount -> row_ptr (absolute positions).
// Replaces csr_sort's count pass + scan.
// ---------------------------------------------------------------------------
__global__ void row_scan_kernel(const int* __restrict__ rcount,
                                const int* __restrict__ bucket_base,
                                int* __restrict__ row_ptr) {
    __shared__ int sc[BROWS];
    int b = blockIdx.x;
    int t = threadIdx.x;
    int n = b * BROWS + t;
    int c = (n < NN) ? rcount[n] : 0;
    sc[t] = c;
    __syncthreads();
    for (int off = 1; off < BROWS; off <<= 1) {
        int u = (t >= off) ? sc[t - off] : 0;
        __syncthreads();
        sc[t] += u;
        __syncthreads();
    }
    if (n <= NN) row_ptr[n] = bucket_base[b] + sc[t] - c;  // n==NN: c=0, excl=total
}

// ---------------------------------------------------------------------------
// CSR build, stage 2: single-pass scatter to row-sorted PACKED edges.
// Cursors come straight from row_ptr; ONE barrier, ONE pass over the bucket.
// bkeys/bvals are dead after this kernel -> nontemporal loads.
// ---------------------------------------------------------------------------
__global__ __launch_bounds__(SORT_T) void csr_sort_kernel(
    const unsigned int* __restrict__ bkeys,
    const float* __restrict__ bvals,
    const int* __restrict__ bucket_base,
    const int* __restrict__ row_ptr,
    unsigned int* __restrict__ edges) {
    __shared__ int curs[BROWS];
    int b = blockIdx.x;
    int beg = bucket_base[b], end = bucket_base[b + 1];
    int t = threadIdx.x;
    if (t < BROWS) {
        int n = b * BROWS + t;
        curs[t] = (n < NN) ? row_ptr[n] : 0;
    }
    __syncthreads();
    for (int i = beg + t; i < end; i += SORT_T) {
        unsigned int k = __builtin_nontemporal_load(&bkeys[i]);
        float v = __builtin_nontemporal_load(&bvals[i]);
        int rl = (k >> 17) & (BROWS - 1);
        int p = atomicAdd(&curs[rl], 1);
        unsigned int vb = f32_to_bf16(v) & 0x7FFFu;   // val>=0
        edges[p] = (k & 0x1FFFF) | (vb << 17);
    }
}

// ---------------------------------------------------------------------------
// Pull-based segment sum, 16-byte gathers (R6/R8 configuration). Edge words
// are a pure stream -> nontemporal loads: keep L2 capacity for the ego rows
// (gather is L2-capacity bound: 154MB L2-miss traffic on a 12.8MB working
// set; stream pollution costs hit rate).
// ---------------------------------------------------------------------------
template <int FO, int UU>
__device__ __forceinline__ void gacc(const uint4* __restrict__ egoh4,
                                     const unsigned int* __restrict__ edges,
                                     int i, int es, int fo, float a[8]) {
    constexpr int ES = 32 / FO;
    unsigned ew[UU];
    uint4 g[UU];
#pragma unroll
    for (int u = 0; u < UU; ++u)
        ew[u] = __builtin_nontemporal_load(&edges[i + u * ES + es]);
#pragma unroll
    for (int u = 0; u < UU; ++u)
        g[u] = egoh4[(size_t)(ew[u] & 0x1FFFFu) * FO + fo];
#pragma unroll
    for (int u = 0; u < UU; ++u) {
        float v = __uint_as_float((ew[u] >> 1) & 0xFFFF0000u);  // bf15 val
        a[0] = fmaf(v, __uint_as_float(g[u].x << 16), a[0]);
        a[1] = fmaf(v, __uint_as_float(g[u].x & 0xFFFF0000u), a[1]);
        a[2] = fmaf(v, __uint_as_float(g[u].y << 16), a[2]);
        a[3] = fmaf(v, __uint_as_float(g[u].y & 0xFFFF0000u), a[3]);
        a[4] = fmaf(v, __uint_as_float(g[u].z << 16), a[4]);
        a[5] = fmaf(v, __uint_as_float(g[u].z & 0xFFFF0000u), a[5]);
        a[6] = fmaf(v, __uint_as_float(g[u].w << 16), a[6]);
        a[7] = fmaf(v, __uint_as_float(g[u].w & 0xFFFF0000u), a[7]);
    }
}

template <int D>
__global__ __launch_bounds__(256) void gather_kernel(
    const uint4* __restrict__ egoh4,   // row = FO uint4 (128B for D=64)
    const unsigned int* __restrict__ edges,
    const int* __restrict__ row_ptr,
    float* __restrict__ side) {
    constexpr int FO = D / 8;          // uint4 per row  (8 for D=64, 4 for D=32)
    constexpr int ES = 32 / FO;        // edges per step (4 for D=64, 8 for D=32)
    const int gt = blockIdx.x * 256 + threadIdx.x;
    const int n  = gt >> 5;            // 32 lanes per node, 2 nodes per wave
    const int li = gt & 31;
    const int es = li / FO;
    const int fo = li % FO;
    if (n >= NN) return;
    int beg = row_ptr[n];
    int end = row_ptr[n + 1];
    float a[8] = {0.f, 0.f, 0.f, 0.f, 0.f, 0.f, 0.f, 0.f};
    int i = beg;
    for (; i + 16 <= end; i += 16) gacc<FO, 16 / ES>(egoh4, edges, i, es, fo, a);
    for (; i + ES <= end; i += ES) gacc<FO, 1>(egoh4, edges, i, es, fo, a);
    if (i + es < end) {                 // tail: < ES edges, predicated
        unsigned ew = __builtin_nontemporal_load(&edges[i + es]);
        uint4 g = egoh4[(size_t)(ew & 0x1FFFFu) * FO + fo];
        float v = __uint_as_float((ew >> 1) & 0xFFFF0000u);
        a[0] = fmaf(v, __uint_as_float(g.x << 16), a[0]);
        a[1] = fmaf(v, __uint_as_float(g.x & 0xFFFF0000u), a[1]);
        a[2] = fmaf(v, __uint_as_float(g.y << 16), a[2]);
        a[3] = fmaf(v, __uint_as_float(g.y & 0xFFFF0000u), a[3]);
        a[4] = fmaf(v, __uint_as_float(g.z << 16), a[4]);
        a[5] = fmaf(v, __uint_as_float(g.z & 0xFFFF0000u), a[5]);
        a[6] = fmaf(v, __uint_as_float(g.w << 16), a[6]);
        a[7] = fmaf(v, __uint_as_float(g.w & 0xFFFF0000u), a[7]);
    }
    // butterfly-reduce across es lanes (stride FO..16, within 32-lane group)
#pragma unroll
    for (int st = FO; st < 32; st <<= 1) {
#pragma unroll
        for (int q = 0; q < 8; ++q) a[q] += __shfl_xor(a[q], st);
    }
    if (es == 0)
        *(float4*)&side[(size_t)n * D + fo * 8] =
            make_float4(a[0], a[1], a[2], a[3]);
    else if (es == 1)
        *(float4*)&side[(size_t)n * D + fo * 8 + 4] =
            make_float4(a[4], a[5], a[6], a[7]);
}

// ---------------------------------------------------------------------------
// Bi-interaction layer + l2norm (R5 v3: proven).
// W staged once as float4 quads in LDS (b128 read, reused across NPT=4
// nodes); s=ego+side, p=ego*side hoisted at staging; broadcast b128 reads;
// unroll 2 keeps register pressure low (VGPR 28, no spill).
// fp32 fmaf, k-ascending: same accumulation order as baseline.
// ---------------------------------------------------------------------------
template <int DIN, int DOUT, int NB>
__global__ __launch_bounds__(256, 4) void layer_kernel(
    const float* __restrict__ ego, int ego_stride,
    const float* __restrict__ side,
    const float* __restrict__ W1, const float* __restrict__ b1,
    const float* __restrict__ W2, const float* __restrict__ b2,
    float* __restrict__ ego_next,            // nullable
    unsigned short* __restrict__ ego_next_h, // nullable
    float* __restrict__ out, int out_off)
{
    constexpr int RW  = DIN + 4;             // row stride: 16B-aligned, bank-spread
    constexpr int CH  = DIN / 4;             // float4 chunks per node
    constexpr int NPT = NB * DOUT / 256;     // nodes per thread
    static_assert(NB * DOUT % 256 == 0, "");
    static_assert(NPT == 4, "register budget tuned for NPT=4");

    __shared__ float sArr[NB][RW];
    __shared__ float pArr[NB][RW];
    __shared__ float4 W1q[CH * DOUT];        // quad (j, k=kg*4..+3) at [kg*DOUT+j]
    __shared__ float4 W2q[CH * DOUT];

    const int node0 = blockIdx.x * NB;

    // ---- W staging: coalesced float4 global read -> LDS quads ----
    for (int t = threadIdx.x; t < CH * DOUT; t += 256) {
        int j  = t / CH;
        int kg = t - j * CH;
        W1q[kg * DOUT + j] = *(const float4*)&W1[j * DIN + kg * 4];
        W2q[kg * DOUT + j] = *(const float4*)&W2[j * DIN + kg * 4];
    }

    // ---- s/p staging: hoisted s=e+sd, p=e*sd; coalesced float4 in ----
    for (int i = threadIdx.x; i < NB * CH; i += 256) {
        int m = i / CH;
        int c = i - m * CH;
        int n = node0 + m;
        if (n < NN) {
            float4 e  = *(const float4*)&ego[(size_t)n * ego_stride + c * 4];
            float4 sd = *(const float4*)&side[(size_t)n * DIN + c * 4];
            *(float4*)&sArr[m][c * 4] =
                make_float4(e.x + sd.x, e.y + sd.y, e.z + sd.z, e.w + sd.w);
            *(float4*)&pArr[m][c * 4] =
                make_float4(e.x * sd.x, e.y * sd.y, e.z * sd.z, e.w * sd.w);
        }
    }
    __syncthreads();

    // ---- transform: thread (j, slot) does output j for nodes slot*NPT.. ----
    const int j     = threadIdx.x % DOUT;
    const int slot  = threadIdx.x / DOUT;
    const int mbase = slot * NPT;

    float acc1[NPT], acc2[NPT];
    {
        float bb1 = b1[j], bb2 = b2[j];
#pragma unroll
        for (int m8 = 0; m8 < NPT; ++m8) { acc1[m8] = bb1; acc2[m8] = bb2; }
    }

#pragma unroll 2
    for (int kg = 0; kg < CH; ++kg) {
        float4 w1 = W1q[kg * DOUT + j];      // b128, reused across NPT nodes
        float4 w2 = W2q[kg * DOUT + j];
#pragma unroll
        for (int m8 = 0; m8 < NPT; ++m8) {
            float4 sv = *(const float4*)&sArr[mbase + m8][kg * 4]; // broadcast b128
            float4 pv = *(const float4*)&pArr[mbase + m8][kg * 4];
            acc1[m8] = fmaf(sv.x, w1.x, acc1[m8]);
            acc1[m8] = fmaf(sv.y, w1.y, acc1[m8]);
            acc1[m8] = fmaf(sv.z, w1.z, acc1[m8]);
            acc1[m8] = fmaf(sv.w, w1.w, acc1[m8]);
            acc2[m8] = fmaf(pv.x, w2.x, acc2[m8]);
            acc2[m8] = fmaf(pv.y, w2.y, acc2[m8]);
            acc2[m8] = fmaf(pv.z, w2.z, acc2[m8]);
            acc2[m8] = fmaf(pv.w, w2.w, acc2[m8]);
        }
    }

    // ---- epilogue: leaky, v, l2norm (width-DOUT shuffle within node group) ----
#pragma unroll
    for (int m8 = 0; m8 < NPT; ++m8) {
        int n = node0 + mbase + m8;
        float s  = acc1[m8]; s  = (s  > 0.0f) ? s  : 0.01f * s;
        float bb = acc2[m8]; bb = (bb > 0.0f) ? bb : 0.01f * bb;
        float v = s + bb;
        float sq = v * v;
#pragma unroll
        for (int off = DOUT / 2; off > 0; off >>= 1)
            sq += __shfl_xor(sq, off, DOUT);
        float norm = sqrtf(sq);
        norm = (norm > 1e-12f) ? norm : 1e-12f;
        if (n < NN) {
            if (ego_next)   ego_next[(size_t)n * DOUT + j] = v;
            if (ego_next_h) ego_next_h[(size_t)n * DOUT + j] = f32_to_bf16(v);
            out[(size_t)n * OUTD + out_off + j] = v / norm;
        }
    }
}

// ---------------------------------------------------------------------------
extern "C" void kernel_launch(void* const* d_in, const int* in_sizes, int n_in,
                              void* d_out, int out_size, void* d_ws, size_t ws_size,
                              hipStream_t stream) {
    const float* aux_info  = (const float*)d_in[0];
    const float* entity    = (const float*)d_in[1];
    const float* aux_W     = (const float*)d_in[2];
    const float* aux_b     = (const float*)d_in[3];
    const float* edge_vals = (const float*)d_in[4];
    const int*   edge_rows = (const int*)d_in[5];
    const int*   edge_cols = (const int*)d_in[6];
    const float* W1_0 = (const float*)d_in[7];
    const float* b1_0 = (const float*)d_in[8];
    const float* W2_0 = (const float*)d_in[9];
    const float* b2_0 = (const float*)d_in[10];
    const float* W1_1 = (const float*)d_in[11];
    const float* b1_1 = (const float*)d_in[12];
    const float* W2_1 = (const float*)d_in[13];
    const float* b2_1 = (const float*)d_in[14];
    float* out = (float*)d_out;

    // workspace layout (4-byte words). Aliases:
    //   bkeys/bvals (stage-1 SoA, dead after csr_sort) <-> side0 (gather64 out)
    //   ego0h (dead after gather64)                    <-> ego1h (layer0 out)
    float* region0 = (float*)d_ws;
    unsigned int* bkeys = (unsigned int*)region0;          // NE words
    float* bvals = region0 + NE;                           // NE words
    float* side0 = region0;                                // alias (NN*64 words)
    unsigned short* ego0h = (unsigned short*)(region0 + (size_t)NE * 2); // NN*32 w
    unsigned short* ego1h = ego0h;                         // alias (NN*16 words)
    unsigned int* edges = (unsigned int*)((float*)ego0h + (size_t)NN * 32); // NE w
    float* ego1  = (float*)(edges + NE);                   // NN*32 words
    float* side1 = ego1 + (size_t)NN * 32;                 // NN*32 words
    int* row_ptr     = (int*)(side1 + (size_t)NN * 32);    // NN+1
    int* bucket_base = row_ptr + NN + 1;                   // NBUCK+1
    int* gcount      = bucket_base + NBUCK + 1;            // NBUCK  (zeroed)
    int* rcount      = gcount + NBUCK;                     // NN     (zeroed)
    int* bhistT      = rcount + NN;                        // NBUCK*FILL_B
    int* cursor      = bhistT + (size_t)NBUCK * FILL_B;    // NBUCK*FILL_B

    // --- CSR build + fused ego ---
    hipMemsetAsync(gcount, 0, (size_t)(NBUCK + NN) * sizeof(int), stream);
    prep_kernel<<<FILL_B + FUSE_B, BLD1_T, 0, stream>>>(
        edge_rows, gcount, bhistT, aux_info, entity, aux_W, aux_b, ego0h, out);
    cursor_scan_kernel<<<NBUCK, 512, 0, stream>>>(bhistT, gcount, bucket_base, cursor);
    bucket_fill_kernel<<<FILL_B, BLD1_T, 0, stream>>>(
        edge_rows, edge_cols, edge_vals, cursor, rcount, bkeys, bvals);
    row_scan_kernel<<<NBUCK, BROWS, 0, stream>>>(rcount, bucket_base, row_ptr);
    csr_sort_kernel<<<NBUCK, SORT_T, 0, stream>>>(
        bkeys, bvals, bucket_base, row_ptr, edges);

    // --- layer 0 segment-sum (pull, bf16, 16B gathers) ---
    gather_kernel<64><<<NN / 8, 256, 0, stream>>>(
        (const uint4*)ego0h, edges, row_ptr, side0);
    // --- layer 0 transform (ego read from out[:,0:64]) -> ego1 (+bf16) ---
    layer_kernel<64, 32, 32><<<(NN + 31) / 32, 256, 0, stream>>>(
        out, OUTD, side0, W1_0, b1_0, W2_0, b2_0, ego1, ego1h, out, 64);
    // --- layer 1 segment-sum (pull, bf16, 16B gathers) ---
    gather_kernel<32><<<NN / 8, 256, 0, stream>>>(
        (const uint4*)ego1h, edges, row_ptr, side1);
    // --- layer 1 transform -> out[:,96:112] ---
    layer_kernel<32, 16, 64><<<(NN + 63) / 64, 256, 0, stream>>>(
        ego1, 32, side1, W1_1, b1_1, W2_1, b2_1, nullptr, nullptr, out, 96);
}

// Round 11
// 365.242 us; speedup vs baseline: 1.3740x; 1.3740x over previous
//
#include <hip/hip_runtime.h>
#include <math.h>

#define NN 100000
#define NE 3200000
#define OUTD 112
#define BROWS 512                 // rows per bucket (9-bit local row)
#define NBUCK 196                 // ceil(NN / BROWS)
#define FILL_CH 8192              // edges per block in hist/fill
#define FILL_B ((NE + FILL_CH - 1) / FILL_CH)   // 391
#define BLD1_T 1024               // threads for prep/bucket_fill (16 waves)
#define SORT_T 1024               // threads for csr_sort
#define FUSE_B ((NN * 16 + BLD1_T - 1) / BLD1_T)   // 1563 fuse blocks (4 feat/thr)

// round-to-nearest-even fp32 -> bf16 (as raw 16 bits)
__device__ inline unsigned short f32_to_bf16(float f) {
    unsigned u = __float_as_uint(f);
    u += 0x7FFFu + ((u >> 16) & 1u);
    return (unsigned short)(u >> 16);
}
__device__ inline float bf16_bits_to_f32(unsigned b) {
    return __uint_as_float(b << 16);
}

// ---------------------------------------------------------------------------
// MERGED prep kernel: blocks [0, FILL_B) do the bucket histogram (persisting
// per-block counts to bhistT); blocks [FILL_B, ...) do the holographic
// fusion, vectorized 4 features/thread.
// NOTE (R10 lesson): do NOT add per-row global atomics here — device-scope
// atomics resolve beyond the per-XCD L2s (non-coherent) and cost an
// HBM-adjacent RMW each (~146 MB extra WRITE for 3.2M atomics).
// ---------------------------------------------------------------------------
__global__ __launch_bounds__(BLD1_T) void prep_kernel(
    const int* __restrict__ rows,
    int* __restrict__ gcount,
    int* __restrict__ bhistT,
    const float* __restrict__ aux_info,
    const float* __restrict__ entity,
    const float* __restrict__ aux_W,
    const float* __restrict__ aux_b,
    unsigned short* __restrict__ ego0h,
    float* __restrict__ out)
{
    __shared__ int h[NBUCK];
    if (blockIdx.x < FILL_B) {
        // ---- bhist part ----
        for (int i = threadIdx.x; i < NBUCK; i += BLD1_T) h[i] = 0;
        __syncthreads();
        int base = blockIdx.x * FILL_CH;
        int nE = NE - base; if (nE > FILL_CH) nE = FILL_CH;
        for (int i = threadIdx.x; i < nE; i += BLD1_T)
            atomicAdd(&h[rows[base + i] >> 9], 1);
        __syncthreads();
        for (int i = threadIdx.x; i < NBUCK; i += BLD1_T) {
            int c = h[i];
            bhistT[i * FILL_B + blockIdx.x] = c;
            if (c) atomicAdd(&gcount[i], c);
        }
    } else {
        // ---- fuse_ego part: thread = (node n, feature quad j0=4q) ----
        int idx = (blockIdx.x - FILL_B) * BLD1_T + threadIdx.x;
        if (idx >= NN * 16) return;
        int n  = idx >> 4;
        int j0 = (idx & 15) * 4;
        float a0 = aux_info[n * 3 + 0];
        float a1 = aux_info[n * 3 + 1];
        float a2 = aux_info[n * 3 + 2];
        float4 w0 = *(const float4*)&aux_W[j0 * 3 + 0];   // 12 floats = rows j0..j0+3
        float4 w1 = *(const float4*)&aux_W[j0 * 3 + 4];
        float4 w2 = *(const float4*)&aux_W[j0 * 3 + 8];
        float4 bq = *(const float4*)&aux_b[j0];
        float4 ev = *(const float4*)&entity[(size_t)n * 64 + j0];
        float4 r;
        r.x = ev.x * (1.0f + tanhf(fmaf(a0, w0.x, fmaf(a1, w0.y, fmaf(a2, w0.z, bq.x)))));
        r.y = ev.y * (1.0f + tanhf(fmaf(a0, w0.w, fmaf(a1, w1.x, fmaf(a2, w1.y, bq.y)))));
        r.z = ev.z * (1.0f + tanhf(fmaf(a0, w1.z, fmaf(a1, w1.w, fmaf(a2, w2.x, bq.z)))));
        r.w = ev.w * (1.0f + tanhf(fmaf(a0, w2.y, fmaf(a1, w2.z, fmaf(a2, w2.w, bq.w)))));
        ushort4 hq;
        hq.x = f32_to_bf16(r.x);
        hq.y = f32_to_bf16(r.y);
        hq.z = f32_to_bf16(r.z);
        hq.w = f32_to_bf16(r.w);
        *(ushort4*)&ego0h[(size_t)n * 64 + j0] = hq;
        *(float4*)&out[(size_t)n * OUTD + j0] = r;
    }
}

// ---------------------------------------------------------------------------
// CSR build, stage 1b: per-bucket exclusive scan over block counts, with the
// bucket-level scan folded in.
// ---------------------------------------------------------------------------
__global__ void cursor_scan_kernel(const int* __restrict__ bhistT,
                                   const int* __restrict__ gcount,
                                   int* __restrict__ bucket_base,
                                   int* __restrict__ cursor) {
    static_assert(FILL_B <= 512, "scan width");
    __shared__ int sh[512];
    __shared__ int bb[256];
    int b = blockIdx.x;            // bucket
    int t = threadIdx.x;           // chunk-block index
    int gv = (t < NBUCK) ? gcount[t] : 0;
    if (t < 256) bb[t] = gv;
    __syncthreads();
    for (int off = 1; off < 256; off <<= 1) {
        int u = (t >= off && t < 256) ? bb[t - off] : 0;
        __syncthreads();
        if (t < 256) bb[t] += u;
        __syncthreads();
    }
    int base_b = (b > 0) ? bb[b - 1] : 0;     // exclusive prefix for bucket b
    if (t == 0) bucket_base[b] = base_b;
    if (b == 0 && t == 0) bucket_base[NBUCK] = bb[NBUCK - 1];
    int v = (t < FILL_B) ? bhistT[b * FILL_B + t] : 0;
    sh[t] = v;
    __syncthreads();
    for (int off = 1; off < 512; off <<= 1) {
        int u = (t >= off) ? sh[t - off] : 0;
        __syncthreads();
        sh[t] += u;
        __syncthreads();
    }
    if (t < FILL_B) cursor[b * FILL_B + t] = base_b + sh[t] - v;
}

// ---------------------------------------------------------------------------
// CSR build, stage 1c: single-pass scatter (R7-R9 proven form: int2 AoS
// writes for 8B write-combining; LDS cursors; no global atomics).
// ---------------------------------------------------------------------------
__global__ void bucket_fill_kernel(const int* __restrict__ rows,
                                   const int* __restrict__ cols,
                                   const float* __restrict__ vals,
                                   const int* __restrict__ cursor,
                                   int2* __restrict__ edges_b) {
    __shared__ int curs[NBUCK];
    int base = blockIdx.x * FILL_CH;
    int nE = NE - base; if (nE > FILL_CH) nE = FILL_CH;
    for (int i = threadIdx.x; i < NBUCK; i += BLD1_T)
        curs[i] = cursor[i * FILL_B + blockIdx.x];
    __syncthreads();
    for (int i = threadIdx.x; i < nE; i += BLD1_T) {
        int r = rows[base + i];
        int p = atomicAdd(&curs[r >> 9], 1);
        edges_b[p] = make_int2(cols[base + i] | ((r & (BROWS - 1)) << 17),
                               __float_as_int(vals[base + i]));
    }
}

// ---------------------------------------------------------------------------
// CSR build, stage 2: within-bucket counting sort -> row-sorted PACKED edges
// (uint32 = col | bf15(val)<<17) + row_ptr. LDS count + scan (R9 form —
// global rcount atomics are structurally worse, see R10).
// ---------------------------------------------------------------------------
__global__ __launch_bounds__(SORT_T) void csr_sort_kernel(
    const int2* __restrict__ edges_b,
    const int* __restrict__ bucket_base,
    unsigned int* __restrict__ edges,
    int* __restrict__ row_ptr) {
    __shared__ int cnt[BROWS];
    __shared__ int scn[BROWS];
    __shared__ int curs[BROWS];
    int b = blockIdx.x;
    int beg = bucket_base[b], end = bucket_base[b + 1];
    int t = threadIdx.x;
    if (t < BROWS) cnt[t] = 0;
    __syncthreads();
    for (int i = beg + t; i < end; i += SORT_T)
        atomicAdd(&cnt[(edges_b[i].x >> 17) & (BROWS - 1)], 1);
    __syncthreads();
    if (t < BROWS) scn[t] = cnt[t];
    __syncthreads();
    for (int off = 1; off < BROWS; off <<= 1) {
        int v = (t >= off && t < BROWS) ? scn[t - off] : 0;
        __syncthreads();
        if (t < BROWS) scn[t] += v;
        __syncthreads();
    }
    if (t < BROWS) {
        int excl = scn[t] - cnt[t];
        int n = b * BROWS + t;
        if (n <= NN) row_ptr[n] = beg + excl;   // n==NN covered by last bucket
        curs[t] = beg + excl;
    }
    __syncthreads();
    for (int i = beg + t; i < end; i += SORT_T) {
        int2 e = edges_b[i];
        int rl = (e.x >> 17) & (BROWS - 1);
        int p = atomicAdd(&curs[rl], 1);
        unsigned int vb = f32_to_bf16(__int_as_float(e.y)) & 0x7FFFu;  // val>=0
        edges[p] = (unsigned int)(e.x & 0x1FFFF) | (vb << 17);
    }
}

// ---------------------------------------------------------------------------
// Pull-based segment sum, 16-byte gathers (R6/R8/R9 configuration —
// empirical sweet spot; FETCH pinned at 154MB across variants -> near the
// random-64B access ceiling, ~2.9 TB/s effective).
// ---------------------------------------------------------------------------
template <int FO, int UU>
__device__ __forceinline__ void gacc(const uint4* __restrict__ egoh4,
                                     const unsigned int* __restrict__ edges,
                                     int i, int es, int fo, float a[8]) {
    constexpr int ES = 32 / FO;
    unsigned ew[UU];
    uint4 g[UU];
#pragma unroll
    for (int u = 0; u < UU; ++u) ew[u] = edges[i + u * ES + es];
#pragma unroll
    for (int u = 0; u < UU; ++u)
        g[u] = egoh4[(size_t)(ew[u] & 0x1FFFFu) * FO + fo];
#pragma unroll
    for (int u = 0; u < UU; ++u) {
        float v = __uint_as_float((ew[u] >> 1) & 0xFFFF0000u);  // bf15 val
        a[0] = fmaf(v, __uint_as_float(g[u].x << 16), a[0]);
        a[1] = fmaf(v, __uint_as_float(g[u].x & 0xFFFF0000u), a[1]);
        a[2] = fmaf(v, __uint_as_float(g[u].y << 16), a[2]);
        a[3] = fmaf(v, __uint_as_float(g[u].y & 0xFFFF0000u), a[3]);
        a[4] = fmaf(v, __uint_as_float(g[u].z << 16), a[4]);
        a[5] = fmaf(v, __uint_as_float(g[u].z & 0xFFFF0000u), a[5]);
        a[6] = fmaf(v, __uint_as_float(g[u].w << 16), a[6]);
        a[7] = fmaf(v, __uint_as_float(g[u].w & 0xFFFF0000u), a[7]);
    }
}

template <int D>
__global__ __launch_bounds__(256) void gather_kernel(
    const uint4* __restrict__ egoh4,   // row = FO uint4 (128B for D=64)
    const unsigned int* __restrict__ edges,
    const int* __restrict__ row_ptr,
    float* __restrict__ side) {
    constexpr int FO = D / 8;          // uint4 per row  (8 for D=64, 4 for D=32)
    constexpr int ES = 32 / FO;        // edges per step (4 for D=64, 8 for D=32)
    const int gt = blockIdx.x * 256 + threadIdx.x;
    const int n  = gt >> 5;            // 32 lanes per node, 2 nodes per wave
    const int li = gt & 31;
    const int es = li / FO;
    const int fo = li % FO;
    if (n >= NN) return;
    int beg = row_ptr[n];
    int end = row_ptr[n + 1];
    float a[8] = {0.f, 0.f, 0.f, 0.f, 0.f, 0.f, 0.f, 0.f};
    int i = beg;
    for (; i + 16 <= end; i += 16) gacc<FO, 16 / ES>(egoh4, edges, i, es, fo, a);
    for (; i + ES <= end; i += ES) gacc<FO, 1>(egoh4, edges, i, es, fo, a);
    if (i + es < end) {                 // tail: < ES edges, predicated
        unsigned ew = edges[i + es];
        uint4 g = egoh4[(size_t)(ew & 0x1FFFFu) * FO + fo];
        float v = __uint_as_float((ew >> 1) & 0xFFFF0000u);
        a[0] = fmaf(v, __uint_as_float(g.x << 16), a[0]);
        a[1] = fmaf(v, __uint_as_float(g.x & 0xFFFF0000u), a[1]);
        a[2] = fmaf(v, __uint_as_float(g.y << 16), a[2]);
        a[3] = fmaf(v, __uint_as_float(g.y & 0xFFFF0000u), a[3]);
        a[4] = fmaf(v, __uint_as_float(g.z << 16), a[4]);
        a[5] = fmaf(v, __uint_as_float(g.z & 0xFFFF0000u), a[5]);
        a[6] = fmaf(v, __uint_as_float(g.w << 16), a[6]);
        a[7] = fmaf(v, __uint_as_float(g.w & 0xFFFF0000u), a[7]);
    }
    // butterfly-reduce across es lanes (stride FO..16, within 32-lane group)
#pragma unroll
    for (int st = FO; st < 32; st <<= 1) {
#pragma unroll
        for (int q = 0; q < 8; ++q) a[q] += __shfl_xor(a[q], st);
    }
    if (es == 0)
        *(float4*)&side[(size_t)n * D + fo * 8] =
            make_float4(a[0], a[1], a[2], a[3]);
    else if (es == 1)
        *(float4*)&side[(size_t)n * D + fo * 8 + 4] =
            make_float4(a[4], a[5], a[6], a[7]);
}

// ---------------------------------------------------------------------------
// Bi-interaction layer + l2norm (R5 v3: proven).
// W staged once as float4 quads in LDS (b128 read, reused across NPT=4
// nodes); s=ego+side, p=ego*side hoisted at staging; broadcast b128 reads;
// unroll 2 keeps register pressure low (VGPR 28, no spill).
// fp32 fmaf, k-ascending: same accumulation order as baseline.
// ---------------------------------------------------------------------------
template <int DIN, int DOUT, int NB>
__global__ __launch_bounds__(256, 4) void layer_kernel(
    const float* __restrict__ ego, int ego_stride,
    const float* __restrict__ side,
    const float* __restrict__ W1, const float* __restrict__ b1,
    const float* __restrict__ W2, const float* __restrict__ b2,
    float* __restrict__ ego_next,            // nullable
    unsigned short* __restrict__ ego_next_h, // nullable
    float* __restrict__ out, int out_off)
{
    constexpr int RW  = DIN + 4;             // row stride: 16B-aligned, bank-spread
    constexpr int CH  = DIN / 4;             // float4 chunks per node
    constexpr int NPT = NB * DOUT / 256;     // nodes per thread
    static_assert(NB * DOUT % 256 == 0, "");
    static_assert(NPT == 4, "register budget tuned for NPT=4");

    __shared__ float sArr[NB][RW];
    __shared__ float pArr[NB][RW];
    __shared__ float4 W1q[CH * DOUT];        // quad (j, k=kg*4..+3) at [kg*DOUT+j]
    __shared__ float4 W2q[CH * DOUT];

    const int node0 = blockIdx.x * NB;

    // ---- W staging: coalesced float4 global read -> LDS quads ----
    for (int t = threadIdx.x; t < CH * DOUT; t += 256) {
        int j  = t / CH;
        int kg = t - j * CH;
        W1q[kg * DOUT + j] = *(const float4*)&W1[j * DIN + kg * 4];
        W2q[kg * DOUT + j] = *(const float4*)&W2[j * DIN + kg * 4];
    }

    // ---- s/p staging: hoisted s=e+sd, p=e*sd; coalesced float4 in ----
    for (int i = threadIdx.x; i < NB * CH; i += 256) {
        int m = i / CH;
        int c = i - m * CH;
        int n = node0 + m;
        if (n < NN) {
            float4 e  = *(const float4*)&ego[(size_t)n * ego_stride + c * 4];
            float4 sd = *(const float4*)&side[(size_t)n * DIN + c * 4];
            *(float4*)&sArr[m][c * 4] =
                make_float4(e.x + sd.x, e.y + sd.y, e.z + sd.z, e.w + sd.w);
            *(float4*)&pArr[m][c * 4] =
                make_float4(e.x * sd.x, e.y * sd.y, e.z * sd.z, e.w * sd.w);
        }
    }
    __syncthreads();

    // ---- transform: thread (j, slot) does output j for nodes slot*NPT.. ----
    const int j     = threadIdx.x % DOUT;
    const int slot  = threadIdx.x / DOUT;
    const int mbase = slot * NPT;

    float acc1[NPT], acc2[NPT];
    {
        float bb1 = b1[j], bb2 = b2[j];
#pragma unroll
        for (int m8 = 0; m8 < NPT; ++m8) { acc1[m8] = bb1; acc2[m8] = bb2; }
    }

#pragma unroll 2
    for (int kg = 0; kg < CH; ++kg) {
        float4 w1 = W1q[kg * DOUT + j];      // b128, reused across NPT nodes
        float4 w2 = W2q[kg * DOUT + j];
#pragma unroll
        for (int m8 = 0; m8 < NPT; ++m8) {
            float4 sv = *(const float4*)&sArr[mbase + m8][kg * 4]; // broadcast b128
            float4 pv = *(const float4*)&pArr[mbase + m8][kg * 4];
            acc1[m8] = fmaf(sv.x, w1.x, acc1[m8]);
            acc1[m8] = fmaf(sv.y, w1.y, acc1[m8]);
            acc1[m8] = fmaf(sv.z, w1.z, acc1[m8]);
            acc1[m8] = fmaf(sv.w, w1.w, acc1[m8]);
            acc2[m8] = fmaf(pv.x, w2.x, acc2[m8]);
            acc2[m8] = fmaf(pv.y, w2.y, acc2[m8]);
            acc2[m8] = fmaf(pv.z, w2.z, acc2[m8]);
            acc2[m8] = fmaf(pv.w, w2.w, acc2[m8]);
        }
    }

    // ---- epilogue: leaky, v, l2norm (width-DOUT shuffle within node group) ----
#pragma unroll
    for (int m8 = 0; m8 < NPT; ++m8) {
        int n = node0 + mbase + m8;
        float s  = acc1[m8]; s  = (s  > 0.0f) ? s  : 0.01f * s;
        float bb = acc2[m8]; bb = (bb > 0.0f) ? bb : 0.01f * bb;
        float v = s + bb;
        float sq = v * v;
#pragma unroll
        for (int off = DOUT / 2; off > 0; off >>= 1)
            sq += __shfl_xor(sq, off, DOUT);
        float norm = sqrtf(sq);
        norm = (norm > 1e-12f) ? norm : 1e-12f;
        if (n < NN) {
            if (ego_next)   ego_next[(size_t)n * DOUT + j] = v;
            if (ego_next_h) ego_next_h[(size_t)n * DOUT + j] = f32_to_bf16(v);
            out[(size_t)n * OUTD + out_off + j] = v / norm;
        }
    }
}

// ---------------------------------------------------------------------------
extern "C" void kernel_launch(void* const* d_in, const int* in_sizes, int n_in,
                              void* d_out, int out_size, void* d_ws, size_t ws_size,
                              hipStream_t stream) {
    const float* aux_info  = (const float*)d_in[0];
    const float* entity    = (const float*)d_in[1];
    const float* aux_W     = (const float*)d_in[2];
    const float* aux_b     = (const float*)d_in[3];
    const float* edge_vals = (const float*)d_in[4];
    const int*   edge_rows = (const int*)d_in[5];
    const int*   edge_cols = (const int*)d_in[6];
    const float* W1_0 = (const float*)d_in[7];
    const float* b1_0 = (const float*)d_in[8];
    const float* W2_0 = (const float*)d_in[9];
    const float* b2_0 = (const float*)d_in[10];
    const float* W1_1 = (const float*)d_in[11];
    const float* b1_1 = (const float*)d_in[12];
    const float* W2_1 = (const float*)d_in[13];
    const float* b2_1 = (const float*)d_in[14];
    float* out = (float*)d_out;

    // workspace layout (4-byte words). Aliases:
    //   edges_b (stage-1, dead after csr_sort)  <->  side0 (written by gather64)
    //   ego0h (dead after gather64)             <->  ego1h (written by layer0)
    float* region0 = (float*)d_ws;
    int2*  edges_b = (int2*)region0;                       // 6.4M words
    float* side0   = region0;                              // alias
    unsigned short* ego0h = (unsigned short*)(region0 + (size_t)NE * 2); // 3.2M words
    unsigned short* ego1h = ego0h;                         // alias (1.6M words)
    unsigned int* edges = (unsigned int*)((float*)ego0h + (size_t)NN * 32); // 3.2M words
    float* ego1  = (float*)(edges + NE);                   // 3.2M words
    float* side1 = ego1 + (size_t)NN * 32;                 // 3.2M words
    int* row_ptr     = (int*)(side1 + (size_t)NN * 32);
    int* bucket_base = row_ptr + NN + 1;
    int* gcount      = bucket_base + NBUCK + 1;
    int* bhistT      = gcount + NBUCK;                     // NBUCK*FILL_B words
    int* cursor      = bhistT + (size_t)NBUCK * FILL_B;    // NBUCK*FILL_B words

    // --- CSR build stage 1a + fused ego (merged, heterogeneous grid) ---
    hipMemsetAsync(gcount, 0, (size_t)NBUCK * sizeof(int), stream);
    prep_kernel<<<FILL_B + FUSE_B, BLD1_T, 0, stream>>>(
        edge_rows, gcount, bhistT, aux_info, entity, aux_W, aux_b, ego0h, out);
    cursor_scan_kernel<<<NBUCK, 512, 0, stream>>>(bhistT, gcount, bucket_base, cursor);
    bucket_fill_kernel<<<FILL_B, BLD1_T, 0, stream>>>(
        edge_rows, edge_cols, edge_vals, cursor, edges_b);
    csr_sort_kernel<<<NBUCK, SORT_T, 0, stream>>>(edges_b, bucket_base, edges, row_ptr);

    // --- layer 0 segment-sum (pull, bf16, 16B gathers) ---
    gather_kernel<64><<<NN / 8, 256, 0, stream>>>(
        (const uint4*)ego0h, edges, row_ptr, side0);
    // --- layer 0 transform (ego read from out[:,0:64]) -> ego1 (+bf16) ---
    layer_kernel<64, 32, 32><<<(NN + 31) / 32, 256, 0, stream>>>(
        out, OUTD, side0, W1_0, b1_0, W2_0, b2_0, ego1, ego1h, out, 64);
    // --- layer 1 segment-sum (pull, bf16, 16B gathers) ---
    gather_kernel<32><<<NN / 8, 256, 0, stream>>>(
        (const uint4*)ego1h, edges, row_ptr, side1);
    // --- layer 1 transform -> out[:,96:112] ---
    layer_kernel<32, 16, 64><<<(NN + 63) / 64, 256, 0, stream>>>(
        ego1, 32, side1, W1_1, b1_1, W2_1, b2_1, nullptr, nullptr, out, 96);
}